// Round 1
// baseline (510.780 us; speedup 1.0000x reference)
//
#include <hip/hip_runtime.h>
#include <hip/hip_bf16.h>
#include <stdint.h>

// Problem constants (fixed by setup_inputs)
#define NTOK   8192
#define TOPK   2
#define NEXP   8
#define DIN    2048
#define DOUT   2048
#define NK     (NTOK*TOPK)

typedef __bf16 bf16_8 __attribute__((ext_vector_type(8)));  // 4 VGPRs, MFMA A/B frag
typedef float  f32x4  __attribute__((ext_vector_type(4)));  // MFMA C/D frag

// CK-style global->LDS direct load, 16B per lane.
// HW semantics: LDS dest = wave-uniform base + lane*16 (m104/m108) — callers
// must pass a wave-uniform LDS pointer and lane-ordered contiguous layout.
__device__ __forceinline__ void gl2lds16(const void* g, void* l) {
  auto gp = reinterpret_cast<const __attribute__((address_space(1))) uint32_t*>(
      reinterpret_cast<uintptr_t>(g));
  auto lp = reinterpret_cast<__attribute__((address_space(3))) uint32_t*>(
      reinterpret_cast<uintptr_t>(l));
  __builtin_amdgcn_global_load_lds(gp, lp, 16, 0, 0);
}

// fp32 -> bf16 (RNE via fptrunc), 8 elems/thread, 16B stores.
__global__ void cvt_f32_bf16(const float4* __restrict__ src,
                             uint4* __restrict__ dst, int n8) {
  int i = blockIdx.x * 256 + threadIdx.x;
  if (i >= n8) return;
  float4 a = src[2 * i];
  float4 b = src[2 * i + 1];
  union { __bf16 h[8]; uint4 u; } r;
  r.h[0] = (__bf16)a.x; r.h[1] = (__bf16)a.y; r.h[2] = (__bf16)a.z; r.h[3] = (__bf16)a.w;
  r.h[4] = (__bf16)b.x; r.h[5] = (__bf16)b.y; r.h[6] = (__bf16)b.z; r.h[7] = (__bf16)b.w;
  dst[i] = r.u;
}

// Grouped GEMM over expert-sorted flat rows.
// Block = 256 threads (4 waves), tile 128(M sorted rows) x 128(N out cols), BK=32.
// Wave w -> 64x64 sub-tile (wm=w>>1, wn=w&1), 4x4 MFMA 16x16x32 bf16.
__global__ __launch_bounds__(256)
void moe_gemm(const __bf16* __restrict__ X,     // [NTOK, DIN] bf16 (converted)
              const __bf16* __restrict__ W,     // [NEXP, DOUT, DIN] bf16 (B^T form)
              const float* __restrict__ gates,  // [NTOK*TOPK]
              const int* __restrict__ ssi,      // sorted_scattered_idxs [NK]
              const int* __restrict__ offs,     // expert_offsets [NEXP] (cumsum)
              float* __restrict__ out)          // [NTOK, DOUT] fp32, pre-zeroed
{
  __shared__ __bf16 lA[128 * 32];   // [row][k], no padding (global_load_lds order)
  __shared__ __bf16 lB[128 * 32];
  __shared__ int   sTok[128];       // clamped token per tile row (for gather)
  __shared__ int   sDst[128];       // dest token or -1 (pad row)
  __shared__ float sGate[128];

  const int tid = threadIdx.x;
  const int bid = blockIdx.x;
  const int nt  = bid & 15;         // 16 N-tiles
  const int mtg = bid >> 4;         // linear M-tile over all experts

  // Map linear M-tile -> (expert, tile-in-segment). Uniform scan of 8 offsets.
  int start = 0, end = 0, e, cum = 0, prev = 0, mloc = 0, found = 0;
  for (e = 0; e < NEXP; ++e) {
    int oe  = offs[e];
    int seg = oe - prev;
    int t   = (seg + 127) >> 7;
    if (mtg < cum + t) { start = prev; end = oe; mloc = mtg - cum; found = 1; break; }
    cum += t; prev = oe;
  }
  if (!found) return;  // pad block beyond total tile count (uniform exit)

  const int m0 = start + mloc * 128;

  if (tid < 128) {
    int p     = m0 + tid;
    int valid = p < end;
    int f     = ssi[valid ? p : (end - 1)];  // clamp keeps gather in-bounds
    int tok   = f >> 1;                      // token = flat / k (k=2)
    sTok[tid]  = tok;
    sDst[tid]  = valid ? tok : -1;
    sGate[tid] = valid ? gates[f] : 0.0f;
  }
  __syncthreads();

  // Staging: thread i loads 16B at (row = j*64 + i/4, kchunk = i&3).
  // LDS byte offset = j*4096 + tid*16  ==  wave base (tid&192)*16 + lane*16.
  const int rs = tid >> 2;
  const int kc = tid & 3;
  const __bf16* pA0 = X + (size_t)sTok[rs]      * DIN + kc * 8;
  const __bf16* pA1 = X + (size_t)sTok[rs + 64] * DIN + kc * 8;
  const __bf16* wB  = W + (size_t)e * DOUT * DIN + (size_t)(nt * 128) * DIN;
  const __bf16* pB0 = wB + (size_t)rs        * DIN + kc * 8;
  const __bf16* pB1 = wB + (size_t)(rs + 64) * DIN + kc * 8;
  char* ldsAb = (char*)lA + (tid & 192) * 16;  // wave-uniform base
  char* ldsBb = (char*)lB + (tid & 192) * 16;

  // Fragment addressing: A frag = A[m=lane&15][k=(lane>>4)*8+j] (m120/m89).
  const int w  = tid >> 6;
  const int l  = tid & 63;
  const int wm = w >> 1, wn = w & 1;
  const int lr = l & 15;
  const int kq = l >> 4;
  const __bf16* aBase = lA + (wm * 64 + lr) * 32 + kq * 8;
  const __bf16* bBase = lB + (wn * 64 + lr) * 32 + kq * 8;

  f32x4 acc[4][4] = {};

  for (int it = 0; it < DIN / 32; ++it) {
    __syncthreads();                   // previous iter's ds_reads done
    gl2lds16(pA0, ldsAb);
    gl2lds16(pA1, ldsAb + 4096);
    gl2lds16(pB0, ldsBb);
    gl2lds16(pB1, ldsBb + 4096);
    pA0 += 32; pA1 += 32; pB0 += 32; pB1 += 32;
    __syncthreads();                   // vmcnt(0) drain -> LDS visible

    bf16_8 af[4], bf[4];
#pragma unroll
    for (int am = 0; am < 4; ++am) af[am] = *(const bf16_8*)(aBase + am * 512);
#pragma unroll
    for (int bn = 0; bn < 4; ++bn) bf[bn] = *(const bf16_8*)(bBase + bn * 512);
#pragma unroll
    for (int am = 0; am < 4; ++am)
#pragma unroll
      for (int bn = 0; bn < 4; ++bn)
        acc[am][bn] = __builtin_amdgcn_mfma_f32_16x16x32_bf16(
            af[am], bf[bn], acc[am][bn], 0, 0, 0);
  }

  // Epilogue: C/D layout col=lane&15, row=(lane>>4)*4+reg (m89/m91).
  // out[token] += gate * acc ; exactly 2 atomic adds land per output element.
  const int colBase = nt * 128 + wn * 64 + lr;
  const int rq = kq * 4;
#pragma unroll
  for (int am = 0; am < 4; ++am) {
#pragma unroll
    for (int v = 0; v < 4; ++v) {
      int rl = wm * 64 + am * 16 + rq + v;
      int t  = sDst[rl];
      if (t < 0) continue;
      float g = sGate[rl];
      float* orow = out + (size_t)t * DOUT + colBase;
#pragma unroll
      for (int bn = 0; bn < 4; ++bn)
        atomicAdd(orow + bn * 16, g * acc[am][bn][v]);
    }
  }
}

extern "C" void kernel_launch(void* const* d_in, const int* in_sizes, int n_in,
                              void* d_out, int out_size, void* d_ws, size_t ws_size,
                              hipStream_t stream) {
  const float* inputs = (const float*)d_in[0];   // [8192, 2048]
  const float* ew     = (const float*)d_in[1];   // [8, 2048, 2048] (E, out, in)
  const float* gates  = (const float*)d_in[2];   // [8192, 2]
  const int*   ssi    = (const int*)d_in[5];     // sorted_scattered_idxs [16384]
  const int*   offs   = (const int*)d_in[6];     // expert_offsets [8]
  float* out = (float*)d_out;

  // ws layout: bf16 weights (64 MB) | bf16 inputs (32 MB) -> needs ~100.7 MB
  __bf16* wsW = (__bf16*)d_ws;
  __bf16* wsX = wsW + (size_t)NEXP * DOUT * DIN;

  const int n8w = NEXP * DOUT * DIN / 8;   // 4194304
  const int n8x = NTOK * DIN / 8;          // 2097152
  cvt_f32_bf16<<<n8w / 256, 256, 0, stream>>>((const float4*)ew, (uint4*)wsW, n8w);
  cvt_f32_bf16<<<n8x / 256, 256, 0, stream>>>((const float4*)inputs, (uint4*)wsX, n8x);
  hipMemsetAsync(d_out, 0, (size_t)NTOK * DOUT * sizeof(float), stream);

  // max M-tiles = 128 + 8 (per-expert ceil padding), 16 N-tiles
  moe_gemm<<<136 * 16, 256, 0, stream>>>(wsX, wsW, gates, ssi, offs, out);
}

// Round 2
// 462.377 us; speedup vs baseline: 1.1047x; 1.1047x over previous
//
#include <hip/hip_runtime.h>
#include <hip/hip_bf16.h>
#include <stdint.h>

// Problem constants (fixed by setup_inputs)
#define NTOK   8192
#define TOPK   2
#define NEXP   8
#define DIN    2048
#define DOUT   2048
#define NK     (NTOK*TOPK)

typedef __bf16 bf16_8 __attribute__((ext_vector_type(8)));  // 4 VGPRs, MFMA A/B frag
typedef float  f32x4  __attribute__((ext_vector_type(4)));  // MFMA C/D frag

// global->LDS direct load, 16B per lane. LDS dest = wave-uniform base + lane*16.
__device__ __forceinline__ void gl2lds16(const void* g, void* l) {
  auto gp = reinterpret_cast<const __attribute__((address_space(1))) uint32_t*>(
      reinterpret_cast<uintptr_t>(g));
  auto lp = reinterpret_cast<__attribute__((address_space(3))) uint32_t*>(
      reinterpret_cast<uintptr_t>(l));
  __builtin_amdgcn_global_load_lds(gp, lp, 16, 0, 0);
}

// fp32 -> bf16 (RNE), 8 elems/thread, 16B stores.
__global__ void cvt_f32_bf16(const float4* __restrict__ src,
                             uint4* __restrict__ dst, int n8) {
  int i = blockIdx.x * 256 + threadIdx.x;
  if (i >= n8) return;
  float4 a = src[2 * i];
  float4 b = src[2 * i + 1];
  union { __bf16 h[8]; uint4 u; } r;
  r.h[0] = (__bf16)a.x; r.h[1] = (__bf16)a.y; r.h[2] = (__bf16)a.z; r.h[3] = (__bf16)a.w;
  r.h[4] = (__bf16)b.x; r.h[5] = (__bf16)b.y; r.h[6] = (__bf16)b.z; r.h[7] = (__bf16)b.w;
  dst[i] = r.u;
}

// Grouped GEMM over expert-sorted flat rows.
// Block = 256 threads (4 waves), tile 128(M) x 128(N), BK=32.
// Wave w -> 64x64 sub-tile, 4x4 MFMA 16x16x32 bf16.
// Epilogue: UNGATED bf16 scatter-store to flat[f, :] by flat idx f = ssi[p].
__global__ __launch_bounds__(256, 4)   // 4 waves/SIMD: 64 arch VGPR + 64 acc = 128
void moe_gemm(const __bf16* __restrict__ X,     // [NTOK, DIN] bf16
              const __bf16* __restrict__ W,     // [NEXP, DOUT, DIN] bf16 (B^T form)
              const int* __restrict__ ssi,      // sorted_scattered_idxs [NK]
              const int* __restrict__ offs,     // expert_offsets [NEXP]
              __bf16* __restrict__ flat)        // [NK, DOUT] bf16 out (ungated)
{
  __shared__ __bf16 lA[128 * 32];   // [row][k], no padding (global_load_lds order)
  __shared__ __bf16 lB[128 * 32];
  __shared__ int   sTok[128];       // clamped token per tile row (gather addr)
  __shared__ int   sF[128];         // flat dest idx or -1 (pad row)

  const int tid = threadIdx.x;
  const int bid = blockIdx.x;
  const int nt  = bid & 15;         // 16 N-tiles
  const int mtg = bid >> 4;         // linear M-tile over all experts

  // Map linear M-tile -> (expert e, tile-in-segment). Uniform scan of 8 offsets.
  int start = 0, end = 0, e, cum = 0, prev = 0, mloc = 0, found = 0;
  for (e = 0; e < NEXP; ++e) {
    int oe  = offs[e];
    int seg = oe - prev;
    int t   = (seg + 127) >> 7;
    if (mtg < cum + t) { start = prev; end = oe; mloc = mtg - cum; found = 1; break; }
    cum += t; prev = oe;
  }
  if (!found) return;  // pad block (uniform exit)

  const int m0 = start + mloc * 128;

  if (tid < 128) {
    int p     = m0 + tid;
    int valid = p < end;
    int f     = ssi[valid ? p : (end - 1)];  // clamp keeps gather in-bounds
    sTok[tid] = f >> 1;                      // token = flat / k (k=2)
    sF[tid]   = valid ? f : -1;
  }
  __syncthreads();

  // Staging: thread i loads 16B at (row = j*64 + i/4, kchunk = i&3).
  // LDS byte offset = j*4096 + tid*16 == wave base (tid&192)*16 + lane*16.
  const int rs = tid >> 2;
  const int kc = tid & 3;
  const __bf16* pA0 = X + (size_t)sTok[rs]      * DIN + kc * 8;
  const __bf16* pA1 = X + (size_t)sTok[rs + 64] * DIN + kc * 8;
  const __bf16* wB  = W + (size_t)e * DOUT * DIN + (size_t)(nt * 128) * DIN;
  const __bf16* pB0 = wB + (size_t)rs        * DIN + kc * 8;
  const __bf16* pB1 = wB + (size_t)(rs + 64) * DIN + kc * 8;
  char* ldsAb = (char*)lA + (tid & 192) * 16;  // wave-uniform base
  char* ldsBb = (char*)lB + (tid & 192) * 16;

  // Fragment addressing: A frag = A[m=lane&15][k=(lane>>4)*8+j].
  const int w  = tid >> 6;
  const int l  = tid & 63;
  const int wm = w >> 1, wn = w & 1;
  const int lr = l & 15;
  const int kq = l >> 4;
  const __bf16* aBase = lA + (wm * 64 + lr) * 32 + kq * 8;
  const __bf16* bBase = lB + (wn * 64 + lr) * 32 + kq * 8;

  f32x4 acc[4][4] = {};

  for (int it = 0; it < DIN / 32; ++it) {
    __syncthreads();                   // previous iter's ds_reads done
    gl2lds16(pA0, ldsAb);
    gl2lds16(pA1, ldsAb + 4096);
    gl2lds16(pB0, ldsBb);
    gl2lds16(pB1, ldsBb + 4096);
    pA0 += 32; pA1 += 32; pB0 += 32; pB1 += 32;
    __syncthreads();                   // vmcnt(0) drain -> LDS visible

    bf16_8 af[4], bf[4];
#pragma unroll
    for (int am = 0; am < 4; ++am) af[am] = *(const bf16_8*)(aBase + am * 512);
#pragma unroll
    for (int bn = 0; bn < 4; ++bn) bf[bn] = *(const bf16_8*)(bBase + bn * 512);
#pragma unroll
    for (int am = 0; am < 4; ++am)
#pragma unroll
      for (int bn = 0; bn < 4; ++bn)
        acc[am][bn] = __builtin_amdgcn_mfma_f32_16x16x32_bf16(
            af[am], bf[bn], acc[am][bn], 0, 0, 0);
  }

  // Epilogue: C/D layout col=lane&15, row=(lane>>4)*4+reg.
  // Plain bf16 stores, ungated; gate applied in combine kernel.
  const int colBase = nt * 128 + wn * 64 + lr;
  const int rq = kq * 4;
#pragma unroll
  for (int am = 0; am < 4; ++am) {
#pragma unroll
    for (int v = 0; v < 4; ++v) {
      int rl = wm * 64 + am * 16 + rq + v;
      int f  = sF[rl];
      if (f < 0) continue;
      __bf16* row = flat + (size_t)f * DOUT + colBase;
#pragma unroll
      for (int bn = 0; bn < 4; ++bn)
        row[bn * 16] = (__bf16)acc[am][bn][v];
    }
  }
}

// out[n, :] = g[2n]*flat[2n, :] + g[2n+1]*flat[2n+1, :]
// One block per token, 8 cols/thread. Writes every d_out element (no memset).
__global__ __launch_bounds__(256)
void combine(const __bf16* __restrict__ flat, const float* __restrict__ gates,
             float* __restrict__ out) {
  const int n = blockIdx.x;
  const int c = threadIdx.x * 8;
  bf16_8 y0 = *(const bf16_8*)(flat + (size_t)(2 * n)     * DOUT + c);
  bf16_8 y1 = *(const bf16_8*)(flat + (size_t)(2 * n + 1) * DOUT + c);
  const float g0 = gates[2 * n];
  const float g1 = gates[2 * n + 1];
  float o[8];
#pragma unroll
  for (int j = 0; j < 8; ++j)
    o[j] = g0 * (float)y0[j] + g1 * (float)y1[j];
  float4* dst = (float4*)(out + (size_t)n * DOUT + c);
  dst[0] = *(float4*)&o[0];
  dst[1] = *(float4*)&o[4];
}

extern "C" void kernel_launch(void* const* d_in, const int* in_sizes, int n_in,
                              void* d_out, int out_size, void* d_ws, size_t ws_size,
                              hipStream_t stream) {
  const float* inputs = (const float*)d_in[0];   // [8192, 2048]
  const float* ew     = (const float*)d_in[1];   // [8, 2048, 2048] (E, out, in)
  const float* gates  = (const float*)d_in[2];   // [8192, 2]
  const int*   ssi    = (const int*)d_in[5];     // sorted_scattered_idxs [16384]
  const int*   offs   = (const int*)d_in[6];     // expert_offsets [8]
  float* out = (float*)d_out;

  // ws layout: bf16 W (64 MB) | bf16 X (32 MB) | bf16 flat out (64 MB)
  __bf16* wsW = (__bf16*)d_ws;
  __bf16* wsX = wsW + (size_t)NEXP * DOUT * DIN;
  __bf16* wsF = wsX + (size_t)NTOK * DIN;

  const int n8w = NEXP * DOUT * DIN / 8;   // 4194304
  const int n8x = NTOK * DIN / 8;          // 2097152
  cvt_f32_bf16<<<n8w / 256, 256, 0, stream>>>((const float4*)ew, (uint4*)wsW, n8w);
  cvt_f32_bf16<<<n8x / 256, 256, 0, stream>>>((const float4*)inputs, (uint4*)wsX, n8x);

  // max M-tiles = 128 + 8 (per-expert ceil padding), 16 N-tiles
  moe_gemm<<<136 * 16, 256, 0, stream>>>(wsX, wsW, ssi, offs, wsF);
  combine<<<NTOK, 256, 0, stream>>>(wsF, gates, out);
}

// Round 3
// 454.764 us; speedup vs baseline: 1.1232x; 1.0167x over previous
//
#include <hip/hip_runtime.h>
#include <hip/hip_bf16.h>
#include <stdint.h>

// Problem constants (fixed by setup_inputs)
#define NTOK   8192
#define TOPK   2
#define NEXP   8
#define DIN    2048
#define DOUT   2048
#define NK     (NTOK*TOPK)

typedef __bf16 bf16_8 __attribute__((ext_vector_type(8)));  // 4 VGPRs, MFMA A/B frag
typedef float  f32x4  __attribute__((ext_vector_type(4)));  // MFMA C/D frag

// global->LDS direct load, 16B per lane. LDS dest = wave-uniform base + lane*16.
__device__ __forceinline__ void gl2lds16(const void* g, void* l) {
  auto gp = reinterpret_cast<const __attribute__((address_space(1))) uint32_t*>(
      reinterpret_cast<uintptr_t>(g));
  auto lp = reinterpret_cast<__attribute__((address_space(3))) uint32_t*>(
      reinterpret_cast<uintptr_t>(l));
  __builtin_amdgcn_global_load_lds(gp, lp, 16, 0, 0);
}

// Fused fp32 -> bf16 (RNE) for W then X. 8 elems/thread, 16B stores.
// Blocks [0, nW) convert W, blocks [nW, nW+nX) convert X.
__global__ void cvt_all(const float4* __restrict__ w, uint4* __restrict__ wD,
                        const float4* __restrict__ x, uint4* __restrict__ xD,
                        int nW) {
  int b = blockIdx.x;
  const float4* src;
  uint4* dst;
  int i;
  if (b < nW) { src = w; dst = wD; i = b * 256 + threadIdx.x; }
  else        { src = x; dst = xD; i = (b - nW) * 256 + threadIdx.x; }
  float4 a0 = src[2 * i];
  float4 a1 = src[2 * i + 1];
  union { __bf16 h[8]; uint4 u; } r;
  r.h[0] = (__bf16)a0.x; r.h[1] = (__bf16)a0.y; r.h[2] = (__bf16)a0.z; r.h[3] = (__bf16)a0.w;
  r.h[4] = (__bf16)a1.x; r.h[5] = (__bf16)a1.y; r.h[6] = (__bf16)a1.z; r.h[7] = (__bf16)a1.w;
  dst[i] = r.u;
}

// Grouped GEMM over expert-sorted flat rows.
// Block = 256 threads (4 waves), tile 128(M) x 128(N), BK=32, DOUBLE-BUFFERED LDS.
// One __syncthreads per K-iter; global_load_lds for iter it+1 overlaps MFMA of it.
__global__ __launch_bounds__(256, 4)
void moe_gemm(const __bf16* __restrict__ X,     // [NTOK, DIN] bf16
              const __bf16* __restrict__ W,     // [NEXP, DOUT, DIN] bf16 (B^T form)
              const int* __restrict__ ssi,      // sorted_scattered_idxs [NK]
              const int* __restrict__ offs,     // expert_offsets [NEXP]
              __bf16* __restrict__ flat)        // [NK, DOUT] bf16 out (ungated)
{
  __shared__ __bf16 lA[2][128 * 32];  // [buf][row][k] (global_load_lds lane order)
  __shared__ __bf16 lB[2][128 * 32];
  __shared__ int   sTok[128];
  __shared__ int   sF[128];

  const int tid = threadIdx.x;
  const int bid = blockIdx.x;
  const int nt  = bid & 15;         // 16 N-tiles
  const int mtg = bid >> 4;         // linear M-tile over all experts

  // Map linear M-tile -> (expert e, tile-in-segment). Uniform scan of 8 offsets.
  int start = 0, end = 0, e, cum = 0, prev = 0, mloc = 0, found = 0;
  for (e = 0; e < NEXP; ++e) {
    int oe  = offs[e];
    int seg = oe - prev;
    int t   = (seg + 127) >> 7;
    if (mtg < cum + t) { start = prev; end = oe; mloc = mtg - cum; found = 1; break; }
    cum += t; prev = oe;
  }
  if (!found) return;  // pad block (uniform exit)

  const int m0 = start + mloc * 128;

  if (tid < 128) {
    int p     = m0 + tid;
    int valid = p < end;
    int f     = ssi[valid ? p : (end - 1)];  // clamp keeps gather in-bounds
    sTok[tid] = f >> 1;                      // token = flat / k (k=2)
    sF[tid]   = valid ? f : -1;
  }
  __syncthreads();

  // Staging: thread i loads 16B at (row = j*64 + i/4, kchunk = i&3).
  // LDS byte offset within a buffer = j*4096 + tid*16.
  const int rs = tid >> 2;
  const int kc = tid & 3;
  const __bf16* pA0 = X + (size_t)sTok[rs]      * DIN + kc * 8;
  const __bf16* pA1 = X + (size_t)sTok[rs + 64] * DIN + kc * 8;
  const __bf16* wB  = W + (size_t)e * DOUT * DIN + (size_t)(nt * 128) * DIN;
  const __bf16* pB0 = wB + (size_t)rs        * DIN + kc * 8;
  const __bf16* pB1 = wB + (size_t)(rs + 64) * DIN + kc * 8;
  char* ldsAb = (char*)lA + (tid & 192) * 16;  // wave-uniform base, buf0
  char* ldsBb = (char*)lB + (tid & 192) * 16;  // buf1 = +8192 bytes

  // Fragment addressing: A frag = A[m=lane&15][k=(lane>>4)*8+j].
  const int w  = tid >> 6;
  const int l  = tid & 63;
  const int wm = w >> 1, wn = w & 1;
  const int lr = l & 15;
  const int kq = l >> 4;
  const __bf16* aBase = (const __bf16*)lA + (wm * 64 + lr) * 32 + kq * 8;
  const __bf16* bBase = (const __bf16*)lB + (wn * 64 + lr) * 32 + kq * 8;

  // Prologue: stage iter 0 into buf 0.
  gl2lds16(pA0, ldsAb);
  gl2lds16(pA1, ldsAb + 4096);
  gl2lds16(pB0, ldsBb);
  gl2lds16(pB1, ldsBb + 4096);
  pA0 += 32; pA1 += 32; pB0 += 32; pB1 += 32;

  f32x4 acc[4][4] = {};

  for (int it = 0; it < DIN / 32; ++it) {
    const int cur = it & 1;
    // Crossing this barrier: (a) every wave's loads into buf[cur] are complete
    // (vmcnt drain), (b) every wave's ds_reads of buf[cur^1] are complete
    // (lgkmcnt drain) -> safe to read buf[cur] and overwrite buf[cur^1].
    __syncthreads();
    if (it < DIN / 32 - 1) {
      const int nb = cur ^ 1;
      char* a = ldsAb + nb * 8192;
      char* b = ldsBb + nb * 8192;
      gl2lds16(pA0, a);
      gl2lds16(pA1, a + 4096);
      gl2lds16(pB0, b);
      gl2lds16(pB1, b + 4096);
      pA0 += 32; pA1 += 32; pB0 += 32; pB1 += 32;
    }

    const __bf16* aB = aBase + cur * 4096;
    const __bf16* bB = bBase + cur * 4096;
    bf16_8 af[4], bf[4];
#pragma unroll
    for (int am = 0; am < 4; ++am) af[am] = *(const bf16_8*)(aB + am * 512);
#pragma unroll
    for (int bn = 0; bn < 4; ++bn) bf[bn] = *(const bf16_8*)(bB + bn * 512);
#pragma unroll
    for (int am = 0; am < 4; ++am)
#pragma unroll
      for (int bn = 0; bn < 4; ++bn)
        acc[am][bn] = __builtin_amdgcn_mfma_f32_16x16x32_bf16(
            af[am], bf[bn], acc[am][bn], 0, 0, 0);
  }

  // Epilogue: C/D layout col=lane&15, row=(lane>>4)*4+reg.
  // Plain bf16 stores, ungated; gate applied in combine kernel.
  const int colBase = nt * 128 + wn * 64 + lr;
  const int rq = kq * 4;
#pragma unroll
  for (int am = 0; am < 4; ++am) {
#pragma unroll
    for (int v = 0; v < 4; ++v) {
      int rl = wm * 64 + am * 16 + rq + v;
      int f  = sF[rl];
      if (f < 0) continue;
      __bf16* row = flat + (size_t)f * DOUT + colBase;
#pragma unroll
      for (int bn = 0; bn < 4; ++bn)
        row[bn * 16] = (__bf16)acc[am][bn][v];
    }
  }
}

// out[n, :] = g[2n]*flat[2n, :] + g[2n+1]*flat[2n+1, :]
// One block per token, 8 cols/thread. Writes every d_out element (no memset).
__global__ __launch_bounds__(256)
void combine(const __bf16* __restrict__ flat, const float* __restrict__ gates,
             float* __restrict__ out) {
  const int n = blockIdx.x;
  const int c = threadIdx.x * 8;
  bf16_8 y0 = *(const bf16_8*)(flat + (size_t)(2 * n)     * DOUT + c);
  bf16_8 y1 = *(const bf16_8*)(flat + (size_t)(2 * n + 1) * DOUT + c);
  const float2 g = *(const float2*)(gates + 2 * n);
  float o[8];
#pragma unroll
  for (int j = 0; j < 8; ++j)
    o[j] = g.x * (float)y0[j] + g.y * (float)y1[j];
  float4* dst = (float4*)(out + (size_t)n * DOUT + c);
  dst[0] = *(float4*)&o[0];
  dst[1] = *(float4*)&o[4];
}

extern "C" void kernel_launch(void* const* d_in, const int* in_sizes, int n_in,
                              void* d_out, int out_size, void* d_ws, size_t ws_size,
                              hipStream_t stream) {
  const float* inputs = (const float*)d_in[0];   // [8192, 2048]
  const float* ew     = (const float*)d_in[1];   // [8, 2048, 2048] (E, out, in)
  const float* gates  = (const float*)d_in[2];   // [8192, 2]
  const int*   ssi    = (const int*)d_in[5];     // sorted_scattered_idxs [16384]
  const int*   offs   = (const int*)d_in[6];     // expert_offsets [8]
  float* out = (float*)d_out;

  // ws layout: bf16 W (64 MB) | bf16 X (32 MB) | bf16 flat out (64 MB)
  __bf16* wsW = (__bf16*)d_ws;
  __bf16* wsX = wsW + (size_t)NEXP * DOUT * DIN;
  __bf16* wsF = wsX + (size_t)NTOK * DIN;

  const int n8w = NEXP * DOUT * DIN / 8;   // 4194304 -> 16384 blocks
  const int n8x = NTOK * DIN / 8;          // 2097152 ->  8192 blocks
  const int nWb = n8w / 256, nXb = n8x / 256;
  cvt_all<<<nWb + nXb, 256, 0, stream>>>((const float4*)ew, (uint4*)wsW,
                                         (const float4*)inputs, (uint4*)wsX, nWb);

  // max M-tiles = 128 + 8 (per-expert ceil padding), 16 N-tiles
  moe_gemm<<<136 * 16, 256, 0, stream>>>(wsX, wsW, ssi, offs, wsF);
  combine<<<NTOK, 256, 0, stream>>>(wsF, gates, out);
}

// Round 4
// 441.583 us; speedup vs baseline: 1.1567x; 1.0298x over previous
//
#include <hip/hip_runtime.h>
#include <hip/hip_bf16.h>
#include <stdint.h>

// Problem constants (fixed by setup_inputs)
#define NTOK   8192
#define TOPK   2
#define NEXP   8
#define DIN    2048
#define DOUT   2048
#define NK     (NTOK*TOPK)

// GEMM tiling
#define BM 256
#define BN 128
#define BK 32

typedef __bf16 bf16_8 __attribute__((ext_vector_type(8)));  // 4 VGPRs, MFMA A/B frag
typedef float  f32x4  __attribute__((ext_vector_type(4)));  // MFMA C/D frag

// global->LDS direct load, 16B per lane. LDS dest = wave-uniform base + lane*16.
__device__ __forceinline__ void gl2lds16(const void* g, void* l) {
  auto gp = reinterpret_cast<const __attribute__((address_space(1))) uint32_t*>(
      reinterpret_cast<uintptr_t>(g));
  auto lp = reinterpret_cast<__attribute__((address_space(3))) uint32_t*>(
      reinterpret_cast<uintptr_t>(l));
  __builtin_amdgcn_global_load_lds(gp, lp, 16, 0, 0);
}

// Fused fp32 -> bf16 (RNE) for W then X. 8 elems/thread, 16B stores.
__global__ void cvt_all(const float4* __restrict__ w, uint4* __restrict__ wD,
                        const float4* __restrict__ x, uint4* __restrict__ xD,
                        int nW) {
  int b = blockIdx.x;
  const float4* src;
  uint4* dst;
  int i;
  if (b < nW) { src = w; dst = wD; i = b * 256 + threadIdx.x; }
  else        { src = x; dst = xD; i = (b - nW) * 256 + threadIdx.x; }
  float4 a0 = src[2 * i];
  float4 a1 = src[2 * i + 1];
  union { __bf16 h[8]; uint4 u; } r;
  r.h[0] = (__bf16)a0.x; r.h[1] = (__bf16)a0.y; r.h[2] = (__bf16)a0.z; r.h[3] = (__bf16)a0.w;
  r.h[4] = (__bf16)a1.x; r.h[5] = (__bf16)a1.y; r.h[6] = (__bf16)a1.z; r.h[7] = (__bf16)a1.w;
  dst[i] = r.u;
}

// Grouped GEMM over expert-sorted flat rows.
// Block = 512 threads (8 waves), tile 256(M) x 128(N), BK=32, double-buffered LDS.
// Wave grid 4(M) x 2(N), wave tile 64x64 as 4x4 MFMA 16x16x32 bf16.
//
// LDS bank-conflict swizzle: row r's 16B chunk q lives at chunk slot q ^ s(r),
// s(r) = (r>>1)&3. Staging lane loads global chunk (tid&3)^((tid>>3)&3) of its
// row (same 64B granule -> coalescing unchanged); reader xors kq by (lr>>1)&3.
// s(r) is invariant under r += multiples of 8, so one formula serves all waves.
__global__ __launch_bounds__(512, 4)
void moe_gemm(const __bf16* __restrict__ X,     // [NTOK, DIN] bf16
              const __bf16* __restrict__ W,     // [NEXP, DOUT, DIN] bf16 (B^T form)
              const int* __restrict__ ssi,      // sorted_scattered_idxs [NK]
              const int* __restrict__ offs,     // expert_offsets [NEXP]
              __bf16* __restrict__ flat)        // [NK, DOUT] bf16 out (ungated)
{
  __shared__ __bf16 lA[2][BM * BK];   // 16 KB per buffer
  __shared__ __bf16 lB[2][BN * BK];   //  8 KB per buffer
  __shared__ int   sTok[BM];
  __shared__ int   sF[BM];

  const int tid = threadIdx.x;
  const int bid = blockIdx.x;
  const int nt  = bid & 15;         // 16 N-tiles
  const int mtg = bid >> 4;         // linear M-tile over all experts

  // Map linear M-tile -> (expert e, tile-in-segment). Uniform scan of 8 offsets.
  int start = 0, end = 0, e, cum = 0, prev = 0, mloc = 0, found = 0;
  for (e = 0; e < NEXP; ++e) {
    int oe  = offs[e];
    int seg = oe - prev;
    int t   = (seg + BM - 1) >> 8;
    if (mtg < cum + t) { start = prev; end = oe; mloc = mtg - cum; found = 1; break; }
    cum += t; prev = oe;
  }
  if (!found) return;  // pad block (uniform exit)

  const int m0 = start + mloc * BM;

  if (tid < BM) {
    int p     = m0 + tid;
    int valid = p < end;
    int f     = ssi[valid ? p : (end - 1)];  // clamp keeps gather in-bounds
    sTok[tid] = f >> 1;                      // token = flat / k (k=2)
    sF[tid]   = valid ? f : -1;
  }
  __syncthreads();

  // Staging: thread tid owns row rs = tid>>2 (A: rs and rs+128; B: rs),
  // swizzled k-chunk kc. LDS dest is forced to tid*16 within each region.
  const int rs = tid >> 2;                       // 0..127
  const int kc = (tid & 3) ^ ((tid >> 3) & 3);   // swizzled chunk
  const __bf16* pA0 = X + (size_t)sTok[rs]       * DIN + kc * 8;
  const __bf16* pA1 = X + (size_t)sTok[rs + 128] * DIN + kc * 8;
  const __bf16* wB  = W + (size_t)e * DOUT * DIN + (size_t)(nt * BN) * DIN;
  const __bf16* pB0 = wB + (size_t)rs * DIN + kc * 8;
  char* ldsAb = (char*)lA + (tid >> 6) * 1024;   // wave-uniform base
  char* ldsBb = (char*)lB + (tid >> 6) * 1024;

  // Fragment addressing: A frag = A[m=lane&15][k=(lane>>4)*8+j], kq swizzled.
  const int w   = tid >> 6;
  const int l   = tid & 63;
  const int wm  = w >> 1, wn = w & 1;            // 4 x 2 wave grid
  const int lr  = l & 15;
  const int kq  = l >> 4;
  const int kqs = kq ^ ((lr >> 1) & 3);          // bank-conflict swizzle
  const __bf16* aBase = (const __bf16*)lA + (wm * 64 + lr) * BK + kqs * 8;
  const __bf16* bBase = (const __bf16*)lB + (wn * 64 + lr) * BK + kqs * 8;

  // Prologue: stage iter 0 into buf 0. A buf = 16 KB (two 8 KB halves), B = 8 KB.
  gl2lds16(pA0, ldsAb);
  gl2lds16(pA1, ldsAb + 8192);
  gl2lds16(pB0, ldsBb);
  pA0 += BK; pA1 += BK; pB0 += BK;

  f32x4 acc[4][4] = {};

  for (int it = 0; it < DIN / BK; ++it) {
    const int cur = it & 1;
    // Barrier: all waves' loads into buf[cur] complete (vmcnt drain) and all
    // ds_reads of buf[cur^1] complete (lgkmcnt drain).
    __syncthreads();
    if (it < DIN / BK - 1) {
      const int nb = cur ^ 1;
      gl2lds16(pA0, ldsAb + nb * 16384);
      gl2lds16(pA1, ldsAb + nb * 16384 + 8192);
      gl2lds16(pB0, ldsBb + nb * 8192);
      pA0 += BK; pA1 += BK; pB0 += BK;
    }

    const __bf16* aB = aBase + cur * (BM * BK);
    const __bf16* bB = bBase + cur * (BN * BK);
    bf16_8 af[4], bf[4];
#pragma unroll
    for (int am = 0; am < 4; ++am) af[am] = *(const bf16_8*)(aB + am * 512);
#pragma unroll
    for (int bn = 0; bn < 4; ++bn) bf[bn] = *(const bf16_8*)(bB + bn * 512);
#pragma unroll
    for (int am = 0; am < 4; ++am)
#pragma unroll
      for (int bn = 0; bn < 4; ++bn)
        acc[am][bn] = __builtin_amdgcn_mfma_f32_16x16x32_bf16(
            af[am], bf[bn], acc[am][bn], 0, 0, 0);
  }

  // Epilogue: C/D layout col=lane&15, row=(lane>>4)*4+reg.
  // Plain bf16 stores, ungated; gate applied in combine kernel.
  const int colBase = nt * BN + wn * 64 + lr;
  const int rq = kq * 4;
#pragma unroll
  for (int am = 0; am < 4; ++am) {
#pragma unroll
    for (int v = 0; v < 4; ++v) {
      int rl = wm * 64 + am * 16 + rq + v;
      int f  = sF[rl];
      if (f < 0) continue;
      __bf16* row = flat + (size_t)f * DOUT + colBase;
#pragma unroll
      for (int bn = 0; bn < 4; ++bn)
        row[bn * 16] = (__bf16)acc[am][bn][v];
    }
  }
}

// out[n, :] = g[2n]*flat[2n, :] + g[2n+1]*flat[2n+1, :]
__global__ __launch_bounds__(256)
void combine(const __bf16* __restrict__ flat, const float* __restrict__ gates,
             float* __restrict__ out) {
  const int n = blockIdx.x;
  const int c = threadIdx.x * 8;
  bf16_8 y0 = *(const bf16_8*)(flat + (size_t)(2 * n)     * DOUT + c);
  bf16_8 y1 = *(const bf16_8*)(flat + (size_t)(2 * n + 1) * DOUT + c);
  const float2 g = *(const float2*)(gates + 2 * n);
  float o[8];
#pragma unroll
  for (int j = 0; j < 8; ++j)
    o[j] = g.x * (float)y0[j] + g.y * (float)y1[j];
  float4* dst = (float4*)(out + (size_t)n * DOUT + c);
  dst[0] = *(float4*)&o[0];
  dst[1] = *(float4*)&o[4];
}

extern "C" void kernel_launch(void* const* d_in, const int* in_sizes, int n_in,
                              void* d_out, int out_size, void* d_ws, size_t ws_size,
                              hipStream_t stream) {
  const float* inputs = (const float*)d_in[0];   // [8192, 2048]
  const float* ew     = (const float*)d_in[1];   // [8, 2048, 2048] (E, out, in)
  const float* gates  = (const float*)d_in[2];   // [8192, 2]
  const int*   ssi    = (const int*)d_in[5];     // sorted_scattered_idxs [16384]
  const int*   offs   = (const int*)d_in[6];     // expert_offsets [8]
  float* out = (float*)d_out;

  // ws layout: bf16 W (64 MB) | bf16 X (32 MB) | bf16 flat out (64 MB)
  __bf16* wsW = (__bf16*)d_ws;
  __bf16* wsX = wsW + (size_t)NEXP * DOUT * DIN;
  __bf16* wsF = wsX + (size_t)NTOK * DIN;

  const int n8w = NEXP * DOUT * DIN / 8;   // 4194304 -> 16384 blocks
  const int n8x = NTOK * DIN / 8;          // 2097152 ->  8192 blocks
  const int nWb = n8w / 256, nXb = n8x / 256;
  cvt_all<<<nWb + nXb, 256, 0, stream>>>((const float4*)ew, (uint4*)wsW,
                                         (const float4*)inputs, (uint4*)wsX, nWb);

  // max M-tiles = 64 + 8 (per-expert ceil padding), 16 N-tiles
  moe_gemm<<<72 * 16, 512, 0, stream>>>(wsX, wsW, ssi, offs, wsF);
  combine<<<NTOK, 256, 0, stream>>>(wsF, gates, out);
}